// Round 2
// baseline (1327.038 us; speedup 1.0000x reference)
//
#include <hip/hip_runtime.h>

// PMField R2: split each particle across 2 lanes (32 dims each).
// Working set per lane: z-half(8 f4) + g-half(8 f4) + crow-half(8 f4) ~ 100 VGPR
// -> register-resident (R1's 200-float set spilled: VGPR_Count=72 = scratch arrays).
// Center half-row read ONCE per (b,c) pair from LDS (broadcast b128, 2-way = free),
// reused for dot and g-accumulate. Full dot via one __shfl_xor(.,32).
// rsq/rcp builtins replace precise sqrt/fdiv (~1e-7 rel err, negligible vs thresh).

#define C_N   256
#define STEPS 8
#define DTB   0.15f    // DT * BETA
#define EPSF  1e-4f

__device__ __forceinline__ float4 f4_mul(float4 a, float4 b) {
    return make_float4(a.x * b.x, a.y * b.y, a.z * b.z, a.w * b.w);
}
__device__ __forceinline__ float4 f4_fma(float4 a, float4 b, float4 c) {
    return make_float4(fmaf(a.x, b.x, c.x), fmaf(a.y, b.y, c.y),
                       fmaf(a.z, b.z, c.z), fmaf(a.w, b.w, c.w));
}
__device__ __forceinline__ float4 f4_sfma(float s, float4 b, float4 c) {
    return make_float4(fmaf(s, b.x, c.x), fmaf(s, b.y, c.y),
                       fmaf(s, b.z, c.z), fmaf(s, b.w, c.w));
}

__launch_bounds__(256, 2)
__global__ void pmfield_kernel(const float* __restrict__ z_in,
                               const float* __restrict__ centers,
                               const float* __restrict__ mus,
                               float* __restrict__ z_out) {
    __shared__ float4 s_cent[C_N * 16];   // centers, row-major [c][16 float4] = 64 KB
    __shared__ float2 s_cm[C_N];          // (|c|^2, mu)

    const int tid = threadIdx.x;

    // Stage centers (coalesced: flat float4 array, 256 thr x 16 iters).
    const float4* cg = (const float4*)centers;
#pragma unroll
    for (int k = 0; k < 16; ++k)
        s_cent[k * 256 + tid] = cg[k * 256 + tid];

    // |c|^2 and mu for center `tid` (one-time, from global/L2).
    {
        const float* cr = centers + tid * 64;
        float a0 = 0.f, a1 = 0.f, a2 = 0.f, a3 = 0.f;
#pragma unroll
        for (int d = 0; d < 64; d += 4) {
            a0 = fmaf(cr[d],     cr[d],     a0);
            a1 = fmaf(cr[d + 1], cr[d + 1], a1);
            a2 = fmaf(cr[d + 2], cr[d + 2], a2);
            a3 = fmaf(cr[d + 3], cr[d + 3], a3);
        }
        s_cm[tid] = make_float2((a0 + a1) + (a2 + a3), mus[tid]);
    }
    __syncthreads();

    const int lane  = tid & 63;
    const int pslot = lane & 31;     // particle slot within wave
    const int half  = lane >> 5;     // 0: dims 0-31, 1: dims 32-63
    const int wavei = tid >> 6;
    const int particle = blockIdx.x * 128 + wavei * 32 + pslot;

    const float4* zp = (const float4*)(z_in + (size_t)particle * 64) + half * 8;
    float4 z0 = zp[0], z1 = zp[1], z2 = zp[2], z3 = zp[3],
           z4 = zp[4], z5 = zp[5], z6 = zp[6], z7 = zp[7];

    const float4* chalf = s_cent + half * 8;

    for (int s = 0; s < STEPS; ++s) {
        // zz = |z|^2 (full, via cross-half shuffle)
        float4 qa = f4_mul(z0, z0);
        float4 qb = f4_mul(z1, z1);
        qa = f4_fma(z2, z2, qa);  qb = f4_fma(z3, z3, qb);
        qa = f4_fma(z4, z4, qa);  qb = f4_fma(z5, z5, qb);
        qa = f4_fma(z6, z6, qa);  qb = f4_fma(z7, z7, qb);
        const float zzh = ((qa.x + qb.x) + (qa.y + qb.y))
                        + ((qa.z + qb.z) + (qa.w + qb.w));
        const float zz = zzh + __shfl_xor(zzh, 32, 64);

        float4 g0 = make_float4(0, 0, 0, 0), g1 = g0, g2 = g0, g3 = g0,
               g4 = g0, g5 = g0, g6 = g0, g7 = g0;
        float nacc = 0.f, sw = 0.f;

        for (int c = 0; c < C_N; ++c) {
            const float4* cr = chalf + c * 16;
            const float4 c0 = cr[0], c1 = cr[1], c2 = cr[2], c3 = cr[3],
                         c4 = cr[4], c5 = cr[5], c6 = cr[6], c7 = cr[7];
            const float2 cm = s_cm[c];

            float4 da = f4_mul(z0, c0);
            float4 db = f4_mul(z1, c1);
            da = f4_fma(z2, c2, da);  db = f4_fma(z3, c3, db);
            da = f4_fma(z4, c4, da);  db = f4_fma(z5, c5, db);
            da = f4_fma(z6, c6, da);  db = f4_fma(z7, c7, db);
            const float doth = ((da.x + db.x) + (da.y + db.y))
                             + ((da.z + db.z) + (da.w + db.w));
            const float dot = doth + __shfl_xor(doth, 32, 64);

            const float r2  = fmaxf(fmaf(-2.0f, dot, zz + cm.x), 0.0f) + EPSF;
            const float rin = __builtin_amdgcn_rsqf(r2);   // 1/r
            const float mur = cm.y * rin;                  // mu/r
            nacc += mur;
            const float w = mur * (rin * rin);             // mu/r^3
            sw += w;

            g0 = f4_sfma(w, c0, g0);  g1 = f4_sfma(w, c1, g1);
            g2 = f4_sfma(w, c2, g2);  g3 = f4_sfma(w, c3, g3);
            g4 = f4_sfma(w, c4, g4);  g5 = f4_sfma(w, c5, g5);
            g6 = f4_sfma(w, c6, g6);  g7 = f4_sfma(w, c7, g7);
        }

        const float t = DTB * __builtin_amdgcn_rcpf(1.0f + nacc);
        // z = clamp(z + t*(g - z*sw), -3, 3)
#define PM_UPD(zi, gi)                                                        \
        {                                                                     \
            float4 h = f4_sfma(-sw, zi, gi);                                  \
            zi.x = fminf(fmaxf(fmaf(t, h.x, zi.x), -3.f), 3.f);               \
            zi.y = fminf(fmaxf(fmaf(t, h.y, zi.y), -3.f), 3.f);               \
            zi.z = fminf(fmaxf(fmaf(t, h.z, zi.z), -3.f), 3.f);               \
            zi.w = fminf(fmaxf(fmaf(t, h.w, zi.w), -3.f), 3.f);               \
        }
        PM_UPD(z0, g0) PM_UPD(z1, g1) PM_UPD(z2, g2) PM_UPD(z3, g3)
        PM_UPD(z4, g4) PM_UPD(z5, g5) PM_UPD(z6, g6) PM_UPD(z7, g7)
#undef PM_UPD
    }

    float4* op = (float4*)(z_out + (size_t)particle * 64) + half * 8;
    op[0] = z0; op[1] = z1; op[2] = z2; op[3] = z3;
    op[4] = z4; op[5] = z5; op[6] = z6; op[7] = z7;
}

extern "C" void kernel_launch(void* const* d_in, const int* in_sizes, int n_in,
                              void* d_out, int out_size, void* d_ws, size_t ws_size,
                              hipStream_t stream) {
    const float* z       = (const float*)d_in[0];
    const float* centers = (const float*)d_in[1];
    const float* mus     = (const float*)d_in[2];
    float* out           = (float*)d_out;

    // 131072 particles, 128 per block (256 threads, 2 lanes/particle)
    pmfield_kernel<<<dim3(1024), dim3(256), 0, stream>>>(z, centers, mus, out);
}

// Round 3
// 1118.237 us; speedup vs baseline: 1.1867x; 1.1867x over previous
//
#include <hip/hip_runtime.h>

// PMField R3: 1 thread per particle, 64 dims in 16 named float4 (z0..z15,
// g0..g15) -> forced VGPR residency. waves_per_eu pinned [2,2] so the
// compiler can't trade registers for occupancy (R1: it spilled z/g to
// scratch at VGPR=72 chasing waves). Centers read at wave-uniform global
// addresses -> s_load into SGPRs (0 VGPR, 0 VALU). cn2/mu via one uniform
// ds_read_b64 per pair. Clamp via v_med3_f32.

#define C_N   256
#define STEPS 8
#define DTB   0.15f    // DT * BETA
#define EPSF  1e-4f

__device__ __forceinline__ float4 f4_mul(float4 a, float4 b) {
    return make_float4(a.x * b.x, a.y * b.y, a.z * b.z, a.w * b.w);
}
__device__ __forceinline__ float4 f4_fma(float4 a, float4 b, float4 c) {
    return make_float4(fmaf(a.x, b.x, c.x), fmaf(a.y, b.y, c.y),
                       fmaf(a.z, b.z, c.z), fmaf(a.w, b.w, c.w));
}
__device__ __forceinline__ float4 f4_sfma(float s, float4 b, float4 c) {
    return make_float4(fmaf(s, b.x, c.x), fmaf(s, b.y, c.y),
                       fmaf(s, b.z, c.z), fmaf(s, b.w, c.w));
}
__device__ __forceinline__ float med3(float x, float lo, float hi) {
    return __builtin_amdgcn_fmed3f(x, lo, hi);
}

__global__ __launch_bounds__(256)
__attribute__((amdgpu_waves_per_eu(2, 2)))
void pmfield_kernel(const float* __restrict__ z_in,
                    const float* __restrict__ centers,
                    const float* __restrict__ mus,
                    float* __restrict__ z_out) {
    __shared__ float2 s_cm[C_N];   // (|c|^2, mu) per center

    const int tid = threadIdx.x;

    // One-time: |c|^2 and mu for center `tid` (thread t -> center t).
    {
        const float* cr = centers + tid * 64;
        float a0 = 0.f, a1 = 0.f, a2 = 0.f, a3 = 0.f;
#pragma unroll
        for (int d = 0; d < 64; d += 4) {
            a0 = fmaf(cr[d],     cr[d],     a0);
            a1 = fmaf(cr[d + 1], cr[d + 1], a1);
            a2 = fmaf(cr[d + 2], cr[d + 2], a2);
            a3 = fmaf(cr[d + 3], cr[d + 3], a3);
        }
        s_cm[tid] = make_float2((a0 + a1) + (a2 + a3), mus[tid]);
    }
    __syncthreads();

    const int pid = blockIdx.x * 256 + tid;
    const float4* zp = (const float4*)(z_in + (size_t)pid * 64);

    float4 z0 = zp[0],  z1 = zp[1],  z2 = zp[2],  z3 = zp[3],
           z4 = zp[4],  z5 = zp[5],  z6 = zp[6],  z7 = zp[7],
           z8 = zp[8],  z9 = zp[9],  z10 = zp[10], z11 = zp[11],
           z12 = zp[12], z13 = zp[13], z14 = zp[14], z15 = zp[15];

    const float4* cbase = (const float4*)centers;

    for (int s = 0; s < STEPS; ++s) {
        // zz = |z|^2
        float4 qa = f4_mul(z0, z0);
        float4 qb = f4_mul(z1, z1);
        qa = f4_fma(z2,  z2,  qa);  qb = f4_fma(z3,  z3,  qb);
        qa = f4_fma(z4,  z4,  qa);  qb = f4_fma(z5,  z5,  qb);
        qa = f4_fma(z6,  z6,  qa);  qb = f4_fma(z7,  z7,  qb);
        qa = f4_fma(z8,  z8,  qa);  qb = f4_fma(z9,  z9,  qb);
        qa = f4_fma(z10, z10, qa);  qb = f4_fma(z11, z11, qb);
        qa = f4_fma(z12, z12, qa);  qb = f4_fma(z13, z13, qb);
        qa = f4_fma(z14, z14, qa);  qb = f4_fma(z15, z15, qb);
        const float zz = ((qa.x + qb.x) + (qa.y + qb.y))
                       + ((qa.z + qb.z) + (qa.w + qb.w));

        float4 g0 = make_float4(0, 0, 0, 0);
        float4 g1 = g0, g2 = g0, g3 = g0, g4 = g0, g5 = g0, g6 = g0, g7 = g0,
               g8 = g0, g9 = g0, g10 = g0, g11 = g0, g12 = g0, g13 = g0,
               g14 = g0, g15 = g0;
        float nacc = 0.f, sw = 0.f;

        for (int c = 0; c < C_N; ++c) {
            const float4* cr = cbase + c * 16;   // wave-uniform address
            const float4 c0 = cr[0],  c1 = cr[1],  c2 = cr[2],  c3 = cr[3],
                         c4 = cr[4],  c5 = cr[5],  c6 = cr[6],  c7 = cr[7],
                         c8 = cr[8],  c9 = cr[9],  c10 = cr[10], c11 = cr[11],
                         c12 = cr[12], c13 = cr[13], c14 = cr[14], c15 = cr[15];
            const float2 cm = s_cm[c];

            float4 da = f4_mul(z0, c0);
            float4 db = f4_mul(z1, c1);
            da = f4_fma(z2,  c2,  da);  db = f4_fma(z3,  c3,  db);
            da = f4_fma(z4,  c4,  da);  db = f4_fma(z5,  c5,  db);
            da = f4_fma(z6,  c6,  da);  db = f4_fma(z7,  c7,  db);
            da = f4_fma(z8,  c8,  da);  db = f4_fma(z9,  c9,  db);
            da = f4_fma(z10, c10, da);  db = f4_fma(z11, c11, db);
            da = f4_fma(z12, c12, da);  db = f4_fma(z13, c13, db);
            da = f4_fma(z14, c14, da);  db = f4_fma(z15, c15, db);
            const float dot = ((da.x + db.x) + (da.y + db.y))
                            + ((da.z + db.z) + (da.w + db.w));

            const float r2  = fmaxf(fmaf(-2.0f, dot, zz + cm.x), 0.0f) + EPSF;
            const float rin = __builtin_amdgcn_rsqf(r2);   // 1/r
            const float mur = cm.y * rin;                  // mu/r
            nacc += mur;
            const float w = mur * (rin * rin);             // mu/r^3
            sw += w;

            g0  = f4_sfma(w, c0,  g0);   g1  = f4_sfma(w, c1,  g1);
            g2  = f4_sfma(w, c2,  g2);   g3  = f4_sfma(w, c3,  g3);
            g4  = f4_sfma(w, c4,  g4);   g5  = f4_sfma(w, c5,  g5);
            g6  = f4_sfma(w, c6,  g6);   g7  = f4_sfma(w, c7,  g7);
            g8  = f4_sfma(w, c8,  g8);   g9  = f4_sfma(w, c9,  g9);
            g10 = f4_sfma(w, c10, g10);  g11 = f4_sfma(w, c11, g11);
            g12 = f4_sfma(w, c12, g12);  g13 = f4_sfma(w, c13, g13);
            g14 = f4_sfma(w, c14, g14);  g15 = f4_sfma(w, c15, g15);
        }

        const float t = DTB * __builtin_amdgcn_rcpf(1.0f + nacc);
        // z = med3(z + t*(g - z*sw), -3, 3)
#define PM_UPD(zi, gi)                                                        \
        {                                                                     \
            float4 h = f4_sfma(-sw, zi, gi);                                  \
            zi.x = med3(fmaf(t, h.x, zi.x), -3.f, 3.f);                       \
            zi.y = med3(fmaf(t, h.y, zi.y), -3.f, 3.f);                       \
            zi.z = med3(fmaf(t, h.z, zi.z), -3.f, 3.f);                       \
            zi.w = med3(fmaf(t, h.w, zi.w), -3.f, 3.f);                       \
        }
        PM_UPD(z0, g0)   PM_UPD(z1, g1)   PM_UPD(z2, g2)   PM_UPD(z3, g3)
        PM_UPD(z4, g4)   PM_UPD(z5, g5)   PM_UPD(z6, g6)   PM_UPD(z7, g7)
        PM_UPD(z8, g8)   PM_UPD(z9, g9)   PM_UPD(z10, g10) PM_UPD(z11, g11)
        PM_UPD(z12, g12) PM_UPD(z13, g13) PM_UPD(z14, g14) PM_UPD(z15, g15)
#undef PM_UPD
    }

    float4* op = (float4*)(z_out + (size_t)pid * 64);
    op[0] = z0;   op[1] = z1;   op[2] = z2;   op[3] = z3;
    op[4] = z4;   op[5] = z5;   op[6] = z6;   op[7] = z7;
    op[8] = z8;   op[9] = z9;   op[10] = z10; op[11] = z11;
    op[12] = z12; op[13] = z13; op[14] = z14; op[15] = z15;
}

extern "C" void kernel_launch(void* const* d_in, const int* in_sizes, int n_in,
                              void* d_out, int out_size, void* d_ws, size_t ws_size,
                              hipStream_t stream) {
    const float* z       = (const float*)d_in[0];
    const float* centers = (const float*)d_in[1];
    const float* mus     = (const float*)d_in[2];
    float* out           = (float*)d_out;

    // 131072 particles, 256 per block (1 thread each) -> 512 blocks = 2/CU
    pmfield_kernel<<<dim3(512), dim3(256), 0, stream>>>(z, centers, mus, out);
}

// Round 4
// 268.546 us; speedup vs baseline: 4.9416x; 4.1640x over previous
//
#include <hip/hip_runtime.h>

// PMField R4: MFMA rewrite. S^T = (-2C) @ z^T and G^T = C^T @ W^T with
// particles as the N (col) dimension of 16x16x32 bf16 MFMAs, so zz/n/sw/t
// all key on col=lane&15 (2-shuffle butterflies). Verified layouts only:
//   C/D: col=lane&15, row=(lane>>4)*4+reg   [m89]
//   A:   A[m=lane&15][k=(lane>>4)*8+j]      [m120]
//   B:   B[k=(lane>>4)*8+j][n=lane&15]      (transpose-dual of A)
// Centers in LDS twice: sCS[center][dim] = -2c (S A-operand), sCT[dim][center]
// = c (G A-operand); strides padded to keep b128 16B-aligned + banks spread.
// Per-wave private double scratch for w (bf16) / z-transpose / fp32 io staging.

#define STEPS 8
#define DTB   0.15f
#define EPSF  1e-4f

typedef short bf16x8 __attribute__((ext_vector_type(8)));
typedef float f32x4  __attribute__((ext_vector_type(4)));
union FragU { int4 i; bf16x8 h; };

__device__ __forceinline__ unsigned bf1(float a) {          // round-half-up bf16
    return (__float_as_uint(a) + 0x8000u) >> 16;
}
__device__ __forceinline__ unsigned bfp(float lo, float hi) { // pack 2 bf16
    return ((__float_as_uint(lo) + 0x8000u) >> 16) |
           ((__float_as_uint(hi) + 0x8000u) & 0xFFFF0000u);
}
__device__ __forceinline__ float up_hi(unsigned u) { return __uint_as_float(u & 0xFFFF0000u); }
__device__ __forceinline__ float up_lo(unsigned u) { return __uint_as_float(u << 16); }
__device__ __forceinline__ float med3(float x, float lo, float hi) {
    return __builtin_amdgcn_fmed3f(x, lo, hi);
}

__global__ __launch_bounds__(256, 1)
void pmfield_kernel(const float* __restrict__ z_in,
                    const float* __restrict__ centers,
                    const float* __restrict__ mus,
                    float* __restrict__ z_out) {
    // sCS: [256 centers][72] bf16 (-2c), stride 72 -> 144B rows (16B aligned)
    // sCT: [64 dims][264] bf16 (c),     stride 264 -> 528B rows (16B aligned)
    // sWZ: per-wave 2 buffers of [32][72] bf16 (w / z-bf16 / fp32-io overlay)
    __shared__ unsigned short sCS[256 * 72];
    __shared__ unsigned short sCT[64 * 264];
    __shared__ unsigned       sC2M[256];          // hi=bf16(cn2), lo=bf16(mu)
    __shared__ unsigned short sWZ[4][2][32 * 72];

    unsigned* sCSu = (unsigned*)sCS;   // row stride 36 uints
    unsigned* sCTu = (unsigned*)sCT;   // row stride 132 uints

    const int tid  = threadIdx.x;
    const int lane = tid & 63;
    const int w    = tid >> 6;
    const int m16  = lane & 15;
    const int q    = lane >> 4;

    // ---- prologue: stage centers (both orientations) + cn2/mu ----
    {
        const f32x4* cg = (const f32x4*)(centers + tid * 64);
        float c2 = 0.f;
#pragma unroll
        for (int i = 0; i < 16; ++i) {
            f32x4 v = cg[i];
            c2 = fmaf(v[0], v[0], fmaf(v[1], v[1], fmaf(v[2], v[2], fmaf(v[3], v[3], c2))));
            sCSu[tid * 36 + 2 * i]     = bfp(-2.f * v[0], -2.f * v[1]);
            sCSu[tid * 36 + 2 * i + 1] = bfp(-2.f * v[2], -2.f * v[3]);
            sCT[(4 * i + 0) * 264 + tid] = (unsigned short)bf1(v[0]);
            sCT[(4 * i + 1) * 264 + tid] = (unsigned short)bf1(v[1]);
            sCT[(4 * i + 2) * 264 + tid] = (unsigned short)bf1(v[2]);
            sCT[(4 * i + 3) * 264 + tid] = (unsigned short)bf1(v[3]);
        }
        sC2M[tid] = ((__float_as_uint(c2) + 0x8000u) & 0xFFFF0000u) | bf1(mus[tid]);
    }

    // ---- stage z (coalesced global -> fp32 LDS [32][68] per wave) ----
    const int pbase = blockIdx.x * 128;
    {
        const f32x4* zg = (const f32x4*)(z_in + (size_t)pbase * 64);
#pragma unroll
        for (int k = 0; k < 8; ++k) {
            int idx = k * 256 + tid;
            int p = idx >> 4, c4 = idx & 15;
            float* dst = (float*)&sWZ[p >> 5][0][0];
            *(f32x4*)(dst + (p & 31) * 68 + c4 * 4) = zg[idx];
        }
    }
    __syncthreads();

    // ---- z into C/D-layout registers: z[dimMt][Nt] rows=dims cols=particles ----
    float* fwz = (float*)&sWZ[w][0][0];
    f32x4 z[4][2];
#pragma unroll
    for (int Mt = 0; Mt < 4; ++Mt)
#pragma unroll
        for (int Nt = 0; Nt < 2; ++Nt)
            z[Mt][Nt] = *(const f32x4*)(fwz + (m16 + 16 * Nt) * 68 + 16 * Mt + 4 * q);
    __syncthreads();

    unsigned* zbu = (unsigned*)&sWZ[w][0][0];   // buffer 0 doubles as z-bf16 buf

#pragma unroll 1
    for (int s = 0; s < STEPS; ++s) {
        // zz per particle (col): partial over own regs, butterfly across q-groups
        float zzp[2];
#pragma unroll
        for (int Nt = 0; Nt < 2; ++Nt) {
            float a = 0.f;
#pragma unroll
            for (int Mt = 0; Mt < 4; ++Mt)
#pragma unroll
                for (int r = 0; r < 4; ++r) a = fmaf(z[Mt][Nt][r], z[Mt][Nt][r], a);
            a += __shfl_xor(a, 16, 64);
            a += __shfl_xor(a, 32, 64);
            zzp[Nt] = a;
        }

        // write z (bf16) to buffer0: zbuf[p][dim], 4 dims packed per b64
#pragma unroll
        for (int Mt = 0; Mt < 4; ++Mt)
#pragma unroll
            for (int Nt = 0; Nt < 2; ++Nt) {
                int p = m16 + 16 * Nt;
                unsigned u0 = bfp(z[Mt][Nt][0], z[Mt][Nt][1]);
                unsigned u1 = bfp(z[Mt][Nt][2], z[Mt][Nt][3]);
                *(uint2*)(zbu + p * 36 + 8 * Mt + 2 * q) = make_uint2(u0, u1);
            }
        __syncthreads();

        // z B-frags (held in regs for all chunks)
        FragU zf[2][2];
#pragma unroll
        for (int Kt = 0; Kt < 2; ++Kt)
#pragma unroll
            for (int Nt = 0; Nt < 2; ++Nt) {
                int p = m16 + 16 * Nt;
                zf[Kt][Nt].i = *(const int4*)(zbu + p * 36 + 16 * Kt + 4 * q);
            }

        f32x4 g[4][2];
#pragma unroll
        for (int Mt = 0; Mt < 4; ++Mt)
#pragma unroll
            for (int Nt = 0; Nt < 2; ++Nt) g[Mt][Nt] = (f32x4){0.f, 0.f, 0.f, 0.f};
        float nacc[2] = {0.f, 0.f}, swp[2] = {0.f, 0.f};

#pragma unroll
        for (int c = 0; c < 4; ++c) {             // 4 chunks x 64 centers
            unsigned* wbu = (unsigned*)&sWZ[w][c & 1][0];

            // S^T chunk: rows = centers, cols = particles
            f32x4 S[4][2];
#pragma unroll
            for (int Mt = 0; Mt < 4; ++Mt) {
                int cm = 16 * (4 * c + Mt) + m16;     // center row index
                FragU a0, a1;
                a0.i = *(const int4*)(sCSu + cm * 36 + 4 * q);
                a1.i = *(const int4*)(sCSu + cm * 36 + 16 + 4 * q);
#pragma unroll
                for (int Nt = 0; Nt < 2; ++Nt) {
                    f32x4 acc = (f32x4){0.f, 0.f, 0.f, 0.f};
                    acc = __builtin_amdgcn_mfma_f32_16x16x32_bf16(a0.h, zf[0][Nt].h, acc, 0, 0, 0);
                    acc = __builtin_amdgcn_mfma_f32_16x16x32_bf16(a1.h, zf[1][Nt].h, acc, 0, 0, 0);
                    S[Mt][Nt] = acc;
                }
            }

            // elementwise: r2 -> w (bf16 into wbuf), accumulate n, sw partials
#pragma unroll
            for (int Mt = 0; Mt < 4; ++Mt) {
                uint4 cmv = *(const uint4*)(sC2M + 16 * (4 * c + Mt) + 4 * q);
                float wv[2][4];
#pragma unroll
                for (int r = 0; r < 4; ++r) {
                    unsigned cu = (r == 0) ? cmv.x : (r == 1) ? cmv.y : (r == 2) ? cmv.z : cmv.w;
                    float cn2 = up_hi(cu), mu = up_lo(cu);
#pragma unroll
                    for (int Nt = 0; Nt < 2; ++Nt) {
                        float r2  = fmaxf(S[Mt][Nt][r] + zzp[Nt] + cn2, 0.f) + EPSF;
                        float rin = __builtin_amdgcn_rsqf(r2);
                        float mur = mu * rin;
                        nacc[Nt] += mur;
                        float wval = mur * rin * rin;   // mu / r^3
                        swp[Nt] += wval;
                        wv[Nt][r] = wval;
                    }
                }
#pragma unroll
                for (int Nt = 0; Nt < 2; ++Nt) {
                    int p = m16 + 16 * Nt;
                    unsigned u0 = bfp(wv[Nt][0], wv[Nt][1]);
                    unsigned u1 = bfp(wv[Nt][2], wv[Nt][3]);
                    *(uint2*)(wbu + p * 36 + 8 * Mt + 2 * q) = make_uint2(u0, u1);
                }
            }
            __syncthreads();

            // G^T += C^T(chunk) @ W^T(chunk)
            FragU wf[2][2];
#pragma unroll
            for (int Kt = 0; Kt < 2; ++Kt)
#pragma unroll
                for (int Nt = 0; Nt < 2; ++Nt) {
                    int p = m16 + 16 * Nt;
                    wf[Kt][Nt].i = *(const int4*)(wbu + p * 36 + 16 * Kt + 4 * q);
                }
#pragma unroll
            for (int Mt = 0; Mt < 4; ++Mt) {
                int dm = 16 * Mt + m16;               // dim row index
                FragU ga0, ga1;
                ga0.i = *(const int4*)(sCTu + dm * 132 + 32 * c + 4 * q);
                ga1.i = *(const int4*)(sCTu + dm * 132 + 32 * c + 16 + 4 * q);
#pragma unroll
                for (int Nt = 0; Nt < 2; ++Nt) {
                    g[Mt][Nt] = __builtin_amdgcn_mfma_f32_16x16x32_bf16(ga0.h, wf[0][Nt].h, g[Mt][Nt], 0, 0, 0);
                    g[Mt][Nt] = __builtin_amdgcn_mfma_f32_16x16x32_bf16(ga1.h, wf[1][Nt].h, g[Mt][Nt], 0, 0, 0);
                }
            }
        }

        // reduce n, sw across q-groups; update z
        float tco[2], swf[2];
#pragma unroll
        for (int Nt = 0; Nt < 2; ++Nt) {
            float a = nacc[Nt];
            a += __shfl_xor(a, 16, 64);
            a += __shfl_xor(a, 32, 64);
            float b = swp[Nt];
            b += __shfl_xor(b, 16, 64);
            b += __shfl_xor(b, 32, 64);
            tco[Nt] = DTB * __builtin_amdgcn_rcpf(1.f + a);
            swf[Nt] = b;
        }
#pragma unroll
        for (int Mt = 0; Mt < 4; ++Mt)
#pragma unroll
            for (int Nt = 0; Nt < 2; ++Nt)
#pragma unroll
                for (int r = 0; r < 4; ++r) {
                    float gd = fmaf(-swf[Nt], z[Mt][Nt][r], g[Mt][Nt][r]);
                    z[Mt][Nt][r] = med3(fmaf(tco[Nt], gd, z[Mt][Nt][r]), -3.f, 3.f);
                }
        __syncthreads();   // buffer0 free before next step's z-bf16 write
    }

    // ---- epilogue: fp32 transpose through LDS, coalesced global store ----
#pragma unroll
    for (int Mt = 0; Mt < 4; ++Mt)
#pragma unroll
        for (int Nt = 0; Nt < 2; ++Nt)
            *(f32x4*)(fwz + (m16 + 16 * Nt) * 68 + 16 * Mt + 4 * q) = z[Mt][Nt];
    __syncthreads();
    {
        float* outb = z_out + (size_t)(pbase + 32 * w) * 64;
#pragma unroll
        for (int k = 0; k < 8; ++k) {
            int flat = k * 64 + lane;
            int row = flat >> 4, c4 = flat & 15;
            f32x4 v = *(const f32x4*)(fwz + row * 68 + c4 * 4);
            *(f32x4*)(outb + row * 64 + c4 * 4) = v;
        }
    }
}

extern "C" void kernel_launch(void* const* d_in, const int* in_sizes, int n_in,
                              void* d_out, int out_size, void* d_ws, size_t ws_size,
                              hipStream_t stream) {
    const float* z       = (const float*)d_in[0];
    const float* centers = (const float*)d_in[1];
    const float* mus     = (const float*)d_in[2];
    float* out           = (float*)d_out;

    // 131072 particles / 128 per block (4 waves x 32) = 1024 blocks
    pmfield_kernel<<<dim3(1024), dim3(256), 0, stream>>>(z, centers, mus, out);
}